// Round 1
// baseline (722.150 us; speedup 1.0000x reference)
//
#include <hip/hip_runtime.h>

#define BN 4
#define CH 128
#define NN 4096
#define SCALE_Q 0.088388347648318447f  // 1/sqrt(128)

// ---------------------------------------------------------------------------
// Projection GEMM body: Out[b][o][n] = epilogue( sum_c W[o][c] * X[b][c][n] )
// Block: 256 threads (16x16), tile 128 out-channels x 128 positions,
// K staged in chunks of 32 (W transposed in LDS for float4 reads).
// ---------------------------------------------------------------------------
template <bool RESID>
__device__ __forceinline__ void proj_body(
    const float* __restrict__ Xb,     // [CH][NN] for this batch
    const float* __restrict__ W,      // [CH][CH] row-major [o][c]
    const float* __restrict__ bias,   // [CH]
    float scale,                      // applied as (acc+bias)*scale when !RESID
    float* __restrict__ Ob,           // [CH][NN] for this batch
    const float* __restrict__ Rb,     // residual [CH][NN] (RESID only)
    float g,                          // gamma (RESID only)
    int n0)
{
  const int tid = threadIdx.x;
  const int ty = tid >> 4;   // 0..15
  const int tx = tid & 15;   // 0..15
  const int o0 = ty * 8;
  const int c0 = tx * 8;

  __shared__ float Wl[32][132];  // [k][o], transposed
  __shared__ float Xl[32][132];  // [k][n]

  float acc[8][8];
#pragma unroll
  for (int i = 0; i < 8; ++i)
#pragma unroll
    for (int j = 0; j < 8; ++j) acc[i][j] = 0.f;

  for (int kc = 0; kc < CH; kc += 32) {
    __syncthreads();
    // stage W chunk transposed: Wl[k][o] = W[o][kc+k]
#pragma unroll
    for (int i = 0; i < 4; ++i) {
      int idx = i * 256 + tid;        // 0..1023 float4 units
      int o = idx >> 3;               // 0..127
      int k4 = (idx & 7) * 4;         // 0,4,...,28
      float4 w4 = *reinterpret_cast<const float4*>(&W[o * CH + kc + k4]);
      Wl[k4 + 0][o] = w4.x;
      Wl[k4 + 1][o] = w4.y;
      Wl[k4 + 2][o] = w4.z;
      Wl[k4 + 3][o] = w4.w;
    }
    // stage X chunk: Xl[k][n] = Xb[kc+k][n0+n]
#pragma unroll
    for (int i = 0; i < 4; ++i) {
      int idx = i * 256 + tid;        // 0..1023 float4 units
      int k = idx >> 5;               // 0..31
      int n4 = (idx & 31) * 4;        // 0..124
      *reinterpret_cast<float4*>(&Xl[k][n4]) =
          *reinterpret_cast<const float4*>(&Xb[(size_t)(kc + k) * NN + n0 + n4]);
    }
    __syncthreads();
#pragma unroll 8
    for (int k = 0; k < 32; ++k) {
      float4 a0 = *reinterpret_cast<const float4*>(&Wl[k][o0]);
      float4 a1 = *reinterpret_cast<const float4*>(&Wl[k][o0 + 4]);
      float4 b0 = *reinterpret_cast<const float4*>(&Xl[k][c0]);
      float4 b1 = *reinterpret_cast<const float4*>(&Xl[k][c0 + 4]);
      float a[8] = {a0.x, a0.y, a0.z, a0.w, a1.x, a1.y, a1.z, a1.w};
      float bb[8] = {b0.x, b0.y, b0.z, b0.w, b1.x, b1.y, b1.z, b1.w};
#pragma unroll
      for (int i = 0; i < 8; ++i)
#pragma unroll
        for (int j = 0; j < 8; ++j) acc[i][j] = fmaf(a[i], bb[j], acc[i][j]);
    }
  }

#pragma unroll
  for (int i = 0; i < 8; ++i) {
    float bi = bias[o0 + i];
    size_t row = (size_t)(o0 + i) * NN + n0 + c0;
    if (!RESID) {
      float4 v0, v1;
      v0.x = (acc[i][0] + bi) * scale; v0.y = (acc[i][1] + bi) * scale;
      v0.z = (acc[i][2] + bi) * scale; v0.w = (acc[i][3] + bi) * scale;
      v1.x = (acc[i][4] + bi) * scale; v1.y = (acc[i][5] + bi) * scale;
      v1.z = (acc[i][6] + bi) * scale; v1.w = (acc[i][7] + bi) * scale;
      *reinterpret_cast<float4*>(&Ob[row]) = v0;
      *reinterpret_cast<float4*>(&Ob[row + 4]) = v1;
    } else {
      float4 r0 = *reinterpret_cast<const float4*>(&Rb[row]);
      float4 r1 = *reinterpret_cast<const float4*>(&Rb[row + 4]);
      float4 v0, v1;
      v0.x = g * (acc[i][0] + bi) + r0.x; v0.y = g * (acc[i][1] + bi) + r0.y;
      v0.z = g * (acc[i][2] + bi) + r0.z; v0.w = g * (acc[i][3] + bi) + r0.w;
      v1.x = g * (acc[i][4] + bi) + r1.x; v1.y = g * (acc[i][5] + bi) + r1.y;
      v1.z = g * (acc[i][6] + bi) + r1.z; v1.w = g * (acc[i][7] + bi) + r1.w;
      *reinterpret_cast<float4*>(&Ob[row]) = v0;
      *reinterpret_cast<float4*>(&Ob[row + 4]) = v1;
    }
  }
}

// grid (NN/128, B, 3): z picks Q/K/V
__global__ __launch_bounds__(256) void qkv_proj(
    const float* __restrict__ x,
    const float* __restrict__ wq, const float* __restrict__ bq,
    const float* __restrict__ wk, const float* __restrict__ bk,
    const float* __restrict__ wv, const float* __restrict__ bv,
    float* __restrict__ Q, float* __restrict__ K, float* __restrict__ V)
{
  const int b = blockIdx.y;
  const int n0 = blockIdx.x * 128;
  const float* W; const float* bias; float* Out; float scale;
  if (blockIdx.z == 0)      { W = wq; bias = bq; Out = Q; scale = SCALE_Q; }
  else if (blockIdx.z == 1) { W = wk; bias = bk; Out = K; scale = 1.f; }
  else                      { W = wv; bias = bv; Out = V; scale = 1.f; }
  proj_body<false>(x + (size_t)b * CH * NN, W, bias, scale,
                   Out + (size_t)b * CH * NN, nullptr, 0.f, n0);
}

// grid (NN/128, B): y = gamma*(wo@O + bo) + x
__global__ __launch_bounds__(256) void out_proj(
    const float* __restrict__ O, const float* __restrict__ wo,
    const float* __restrict__ bo, const float* __restrict__ x,
    const float* __restrict__ gamma, float* __restrict__ y)
{
  const int b = blockIdx.y;
  const int n0 = blockIdx.x * 128;
  proj_body<true>(O + (size_t)b * CH * NN, wo, bo, 1.f,
                  y + (size_t)b * CH * NN, x + (size_t)b * CH * NN,
                  gamma[0], n0);
}

// ---------------------------------------------------------------------------
// Flash attention, fp32 vector path.
// Block: 512 threads (16 ty x 32 tx). QB=64 queries, KB=128 keys per tile.
// K and V time-share one LDS buffer; P goes through LDS between the GEMMs.
// Per thread: 4 rows x 4 cols (GEMM1), 4 rows x 4 channels (GEMM2).
// ---------------------------------------------------------------------------
__global__ __launch_bounds__(512) void flash_attn(
    const float* __restrict__ Qg, const float* __restrict__ Kg,
    const float* __restrict__ Vg, float* __restrict__ Og)
{
  // XCD-aware swizzle: 256 blocks -> each XCD gets 32 consecutive logical ids
  // so the 2 XCDs serving one batch hold that batch's 4MB of K+V in L2.
  const int flat = blockIdx.y * 64 + blockIdx.x;
  const int swz = (flat & 7) * 32 + (flat >> 3);
  const int b = swz >> 6;
  const int n0 = (swz & 63) * 64;

  const int tid = threadIdx.x;
  const int ty = tid >> 5;   // 0..15
  const int tx = tid & 31;   // 0..31
  const int r0 = ty * 4;     // 4 query rows
  const int q0 = tx * 4;     // 4 key cols (GEMM1) / 4 channels (GEMM2)

  __shared__ float Qs[CH][68];        // 34.8 KB
  __shared__ float KVs[CH][132];      // 67.6 KB, K then V per k-tile
  __shared__ float Ps[64 * 132];      // 33.8 KB; epilogue reuses as [128][66]

  const float* Qb = Qg + (size_t)b * CH * NN;
  const float* Kb = Kg + (size_t)b * CH * NN;
  const float* Vb = Vg + (size_t)b * CH * NN;

  // load Q tile [128][64]
#pragma unroll
  for (int i = 0; i < 4; ++i) {
    int idx = i * 512 + tid;          // 2048 float4
    int c = idx >> 4;
    int n4 = (idx & 15) * 4;
    *reinterpret_cast<float4*>(&Qs[c][n4]) =
        *reinterpret_cast<const float4*>(&Qb[(size_t)c * NN + n0 + n4]);
  }

  float m_run[4], l_run[4], acc[4][4];
#pragma unroll
  for (int i = 0; i < 4; ++i) {
    m_run[i] = -1e30f; l_run[i] = 0.f;
#pragma unroll
    for (int j = 0; j < 4; ++j) acc[i][j] = 0.f;
  }

  for (int kt = 0; kt < NN / 128; ++kt) {
    const int m0 = kt * 128;
    __syncthreads();  // prev GEMM2 done with KVs (and Q staging visible, iter 0)
    // stage K tile [128][128]
#pragma unroll
    for (int i = 0; i < 8; ++i) {
      int idx = i * 512 + tid;        // 4096 float4
      int c = idx >> 5;
      int m4 = (idx & 31) * 4;
      *reinterpret_cast<float4*>(&KVs[c][m4]) =
          *reinterpret_cast<const float4*>(&Kb[(size_t)c * NN + m0 + m4]);
    }
    __syncthreads();

    // GEMM1: s[r][m] = sum_c Qs[c][r] * KVs[c][m]
    float s[4][4];
#pragma unroll
    for (int i = 0; i < 4; ++i)
#pragma unroll
      for (int j = 0; j < 4; ++j) s[i][j] = 0.f;
#pragma unroll 8
    for (int c = 0; c < CH; ++c) {
      float4 a4 = *reinterpret_cast<const float4*>(&Qs[c][r0]);
      float4 b4 = *reinterpret_cast<const float4*>(&KVs[c][q0]);
      float a[4] = {a4.x, a4.y, a4.z, a4.w};
      float bb[4] = {b4.x, b4.y, b4.z, b4.w};
#pragma unroll
      for (int i = 0; i < 4; ++i)
#pragma unroll
        for (int j = 0; j < 4; ++j) s[i][j] = fmaf(a[i], bb[j], s[i][j]);
    }

    // online softmax; each row lives in 32 consecutive lanes of one wave
    float fscale[4];
#pragma unroll
    for (int i = 0; i < 4; ++i) {
      float mt = fmaxf(fmaxf(s[i][0], s[i][1]), fmaxf(s[i][2], s[i][3]));
#pragma unroll
      for (int off = 16; off >= 1; off >>= 1) mt = fmaxf(mt, __shfl_xor(mt, off));
      float mn = fmaxf(m_run[i], mt);
      float f = __expf(m_run[i] - mn);
      float p0 = __expf(s[i][0] - mn);
      float p1 = __expf(s[i][1] - mn);
      float p2 = __expf(s[i][2] - mn);
      float p3 = __expf(s[i][3] - mn);
      float rs = (p0 + p1) + (p2 + p3);
#pragma unroll
      for (int off = 16; off >= 1; off >>= 1) rs += __shfl_xor(rs, off);
      l_run[i] = l_run[i] * f + rs;
      m_run[i] = mn;
      fscale[i] = f;
      *reinterpret_cast<float4*>(&Ps[(r0 + i) * 132 + q0]) =
          make_float4(p0, p1, p2, p3);
    }
#pragma unroll
    for (int i = 0; i < 4; ++i)
#pragma unroll
      for (int j = 0; j < 4; ++j) acc[i][j] *= fscale[i];

    __syncthreads();  // P written, K reads done
    // stage V tile [128][128] into same buffer
#pragma unroll
    for (int i = 0; i < 8; ++i) {
      int idx = i * 512 + tid;
      int c = idx >> 5;
      int m4 = (idx & 31) * 4;
      *reinterpret_cast<float4*>(&KVs[c][m4]) =
          *reinterpret_cast<const float4*>(&Vb[(size_t)c * NN + m0 + m4]);
    }
    __syncthreads();

    // GEMM2: acc[r][ch] += sum_m Ps[r][m] * KVs[ch][m]
#pragma unroll 2
    for (int m4 = 0; m4 < 128; m4 += 4) {
      float4 p0 = *reinterpret_cast<const float4*>(&Ps[(r0 + 0) * 132 + m4]);
      float4 p1 = *reinterpret_cast<const float4*>(&Ps[(r0 + 1) * 132 + m4]);
      float4 p2 = *reinterpret_cast<const float4*>(&Ps[(r0 + 2) * 132 + m4]);
      float4 p3 = *reinterpret_cast<const float4*>(&Ps[(r0 + 3) * 132 + m4]);
      float4 v0 = *reinterpret_cast<const float4*>(&KVs[q0 + 0][m4]);
      float4 v1 = *reinterpret_cast<const float4*>(&KVs[q0 + 1][m4]);
      float4 v2 = *reinterpret_cast<const float4*>(&KVs[q0 + 2][m4]);
      float4 v3 = *reinterpret_cast<const float4*>(&KVs[q0 + 3][m4]);
      const float4 pr[4] = {p0, p1, p2, p3};
      const float4 vr[4] = {v0, v1, v2, v3};
#pragma unroll
      for (int i = 0; i < 4; ++i)
#pragma unroll
        for (int j = 0; j < 4; ++j) {
          acc[i][j] = fmaf(pr[i].x, vr[j].x, acc[i][j]);
          acc[i][j] = fmaf(pr[i].y, vr[j].y, acc[i][j]);
          acc[i][j] = fmaf(pr[i].z, vr[j].z, acc[i][j]);
          acc[i][j] = fmaf(pr[i].w, vr[j].w, acc[i][j]);
        }
    }
  }

  // finalize: divide by l, transpose through LDS, coalesced store as [CH][NN]
  float inv[4];
#pragma unroll
  for (int i = 0; i < 4; ++i) inv[i] = 1.f / l_run[i];
  __syncthreads();  // last GEMM2 reads of Ps done before overwrite
#pragma unroll
  for (int i = 0; i < 4; ++i)
#pragma unroll
    for (int j = 0; j < 4; ++j)
      Ps[(q0 + j) * 66 + (r0 + i)] = acc[i][j] * inv[i];
  __syncthreads();
  float* Ob = Og + (size_t)b * CH * NN;
#pragma unroll
  for (int i = 0; i < 16; ++i) {
    int idx = i * 512 + tid;          // 8192 floats
    int ch = idx >> 6;
    int n = idx & 63;
    Ob[(size_t)ch * NN + n0 + n] = Ps[ch * 66 + n];
  }
}

// ---------------------------------------------------------------------------
extern "C" void kernel_launch(void* const* d_in, const int* in_sizes, int n_in,
                              void* d_out, int out_size, void* d_ws, size_t ws_size,
                              hipStream_t stream) {
  const float* x     = (const float*)d_in[0];
  const float* wq    = (const float*)d_in[1];
  const float* bq    = (const float*)d_in[2];
  const float* wk    = (const float*)d_in[3];
  const float* bk    = (const float*)d_in[4];
  const float* wv    = (const float*)d_in[5];
  const float* bv    = (const float*)d_in[6];
  const float* wo    = (const float*)d_in[7];
  const float* bo    = (const float*)d_in[8];
  const float* gamma = (const float*)d_in[9];
  float* y = (float*)d_out;

  const size_t per = (size_t)BN * CH * NN;  // 2M floats = 8MB
  float* Q = (float*)d_ws;
  float* K = Q + per;
  float* V = K + per;
  float* O = V + per;

  qkv_proj<<<dim3(NN / 128, BN, 3), 256, 0, stream>>>(x, wq, bq, wk, bk, wv, bv, Q, K, V);
  flash_attn<<<dim3(64, BN), 512, 0, stream>>>(Q, K, V, O);
  out_proj<<<dim3(NN / 128, BN), 256, 0, stream>>>(O, wo, bo, x, gamma, y);
}

// Round 2
// 257.552 us; speedup vs baseline: 2.8039x; 2.8039x over previous
//
#include <hip/hip_runtime.h>

#define BN 4
#define CH 128
#define NN 4096
#define SCALE_Q 0.088388347648318447f  // 1/sqrt(128)

typedef __attribute__((ext_vector_type(8))) short s8b;            // 8 x bf16 (4 VGPR)
typedef __attribute__((ext_vector_type(4))) float f32x4;          // MFMA C/D
typedef __attribute__((ext_vector_type(8))) unsigned short us8;

#define MFMA16(a, b, c) __builtin_amdgcn_mfma_f32_16x16x32_bf16((a), (b), (c), 0, 0, 0)

#define GLOAD16(gsrc, ldst) __builtin_amdgcn_global_load_lds( \
    (const __attribute__((address_space(1))) unsigned int*)(gsrc), \
    (__attribute__((address_space(3))) unsigned int*)(ldst), 16, 0, 0)

__device__ __forceinline__ unsigned short f2bf(float f) {
  union { float f; unsigned int u; } v; v.f = f;
  unsigned int r = v.u + 0x7fffu + ((v.u >> 16) & 1u);  // RNE
  return (unsigned short)(r >> 16);
}

// ---------------------------------------------------------------------------
// QKV projection: fp32 GEMM, epilogue writes bf16.
// Q,K written TRANSPOSED [N][C] (MFMA fragment layout); V natural [C][N].
// Q pre-scaled by 1/sqrt(C). grid (NN/128, B, 3), 256 threads.
// ---------------------------------------------------------------------------
__global__ __launch_bounds__(256) void qkv_proj(
    const float* __restrict__ x,
    const float* __restrict__ wq, const float* __restrict__ bq,
    const float* __restrict__ wk, const float* __restrict__ bk,
    const float* __restrict__ wv, const float* __restrict__ bv,
    unsigned short* __restrict__ Qt, unsigned short* __restrict__ Kt,
    unsigned short* __restrict__ Vn)
{
  const int b = blockIdx.y;
  const int n0 = blockIdx.x * 128;
  const int z = blockIdx.z;
  const float* W; const float* bias;
  if (z == 0)      { W = wq; bias = bq; }
  else if (z == 1) { W = wk; bias = bk; }
  else             { W = wv; bias = bv; }
  const float* Xb = x + (size_t)b * CH * NN;

  const int tid = threadIdx.x;
  const int ty = tid >> 4;   // 0..15
  const int tx = tid & 15;   // 0..15
  const int o0 = ty * 8;
  const int c0 = tx * 8;

  __shared__ float Wl[32][132];
  __shared__ float Xl[32][132];

  float acc[8][8];
#pragma unroll
  for (int i = 0; i < 8; ++i)
#pragma unroll
    for (int j = 0; j < 8; ++j) acc[i][j] = 0.f;

  for (int kc = 0; kc < CH; kc += 32) {
    __syncthreads();
#pragma unroll
    for (int i = 0; i < 4; ++i) {
      int idx = i * 256 + tid;
      int o = idx >> 3;
      int k4 = (idx & 7) * 4;
      float4 w4 = *reinterpret_cast<const float4*>(&W[o * CH + kc + k4]);
      Wl[k4 + 0][o] = w4.x;
      Wl[k4 + 1][o] = w4.y;
      Wl[k4 + 2][o] = w4.z;
      Wl[k4 + 3][o] = w4.w;
    }
#pragma unroll
    for (int i = 0; i < 4; ++i) {
      int idx = i * 256 + tid;
      int k = idx >> 5;
      int n4 = (idx & 31) * 4;
      *reinterpret_cast<float4*>(&Xl[k][n4]) =
          *reinterpret_cast<const float4*>(&Xb[(size_t)(kc + k) * NN + n0 + n4]);
    }
    __syncthreads();
#pragma unroll 8
    for (int k = 0; k < 32; ++k) {
      float4 a0 = *reinterpret_cast<const float4*>(&Wl[k][o0]);
      float4 a1 = *reinterpret_cast<const float4*>(&Wl[k][o0 + 4]);
      float4 b0 = *reinterpret_cast<const float4*>(&Xl[k][c0]);
      float4 b1 = *reinterpret_cast<const float4*>(&Xl[k][c0 + 4]);
      float a[8] = {a0.x, a0.y, a0.z, a0.w, a1.x, a1.y, a1.z, a1.w};
      float bb[8] = {b0.x, b0.y, b0.z, b0.w, b1.x, b1.y, b1.z, b1.w};
#pragma unroll
      for (int i = 0; i < 8; ++i)
#pragma unroll
        for (int j = 0; j < 8; ++j) acc[i][j] = fmaf(a[i], bb[j], acc[i][j]);
    }
  }

  if (z < 2) {
    unsigned short* T = (z == 0 ? Qt : Kt) + (size_t)b * NN * CH;
    const float s = (z == 0) ? SCALE_Q : 1.f;
#pragma unroll
    for (int j = 0; j < 8; ++j) {
      us8 row;
#pragma unroll
      for (int i = 0; i < 8; ++i) row[i] = f2bf((acc[i][j] + bias[o0 + i]) * s);
      *reinterpret_cast<us8*>(T + (size_t)(n0 + c0 + j) * CH + o0) = row;
    }
  } else {
    unsigned short* V = Vn + (size_t)b * CH * NN;
#pragma unroll
    for (int i = 0; i < 8; ++i) {
      us8 row;
      float bi = bias[o0 + i];
#pragma unroll
      for (int j = 0; j < 8; ++j) row[j] = f2bf(acc[i][j] + bi);
      *reinterpret_cast<us8*>(V + (size_t)(o0 + i) * NN + n0 + c0) = row;
    }
  }
}

// ---------------------------------------------------------------------------
// Output projection: fp32, with gamma*(.)+x residual epilogue. Unchanged.
// ---------------------------------------------------------------------------
__global__ __launch_bounds__(256) void out_proj(
    const float* __restrict__ O, const float* __restrict__ wo,
    const float* __restrict__ bo, const float* __restrict__ x,
    const float* __restrict__ gamma, float* __restrict__ y)
{
  const int b = blockIdx.y;
  const int n0 = blockIdx.x * 128;
  const float* Xb = O + (size_t)b * CH * NN;
  const float* Rb = x + (size_t)b * CH * NN;
  float* Ob = y + (size_t)b * CH * NN;
  const float g = gamma[0];

  const int tid = threadIdx.x;
  const int ty = tid >> 4;
  const int tx = tid & 15;
  const int o0 = ty * 8;
  const int c0 = tx * 8;

  __shared__ float Wl[32][132];
  __shared__ float Xl[32][132];

  float acc[8][8];
#pragma unroll
  for (int i = 0; i < 8; ++i)
#pragma unroll
    for (int j = 0; j < 8; ++j) acc[i][j] = 0.f;

  for (int kc = 0; kc < CH; kc += 32) {
    __syncthreads();
#pragma unroll
    for (int i = 0; i < 4; ++i) {
      int idx = i * 256 + tid;
      int o = idx >> 3;
      int k4 = (idx & 7) * 4;
      float4 w4 = *reinterpret_cast<const float4*>(&wo[o * CH + kc + k4]);
      Wl[k4 + 0][o] = w4.x;
      Wl[k4 + 1][o] = w4.y;
      Wl[k4 + 2][o] = w4.z;
      Wl[k4 + 3][o] = w4.w;
    }
#pragma unroll
    for (int i = 0; i < 4; ++i) {
      int idx = i * 256 + tid;
      int k = idx >> 5;
      int n4 = (idx & 31) * 4;
      *reinterpret_cast<float4*>(&Xl[k][n4]) =
          *reinterpret_cast<const float4*>(&Xb[(size_t)(kc + k) * NN + n0 + n4]);
    }
    __syncthreads();
#pragma unroll 8
    for (int k = 0; k < 32; ++k) {
      float4 a0 = *reinterpret_cast<const float4*>(&Wl[k][o0]);
      float4 a1 = *reinterpret_cast<const float4*>(&Wl[k][o0 + 4]);
      float4 b0 = *reinterpret_cast<const float4*>(&Xl[k][c0]);
      float4 b1 = *reinterpret_cast<const float4*>(&Xl[k][c0 + 4]);
      float a[8] = {a0.x, a0.y, a0.z, a0.w, a1.x, a1.y, a1.z, a1.w};
      float bb[8] = {b0.x, b0.y, b0.z, b0.w, b1.x, b1.y, b1.z, b1.w};
#pragma unroll
      for (int i = 0; i < 8; ++i)
#pragma unroll
        for (int j = 0; j < 8; ++j) acc[i][j] = fmaf(a[i], bb[j], acc[i][j]);
    }
  }

#pragma unroll
  for (int i = 0; i < 8; ++i) {
    float bi = bo[o0 + i];
    size_t row = (size_t)(o0 + i) * NN + n0 + c0;
    float4 r0 = *reinterpret_cast<const float4*>(&Rb[row]);
    float4 r1 = *reinterpret_cast<const float4*>(&Rb[row + 4]);
    float4 v0, v1;
    v0.x = g * (acc[i][0] + bi) + r0.x; v0.y = g * (acc[i][1] + bi) + r0.y;
    v0.z = g * (acc[i][2] + bi) + r0.z; v0.w = g * (acc[i][3] + bi) + r0.w;
    v1.x = g * (acc[i][4] + bi) + r1.x; v1.y = g * (acc[i][5] + bi) + r1.y;
    v1.z = g * (acc[i][6] + bi) + r1.z; v1.w = g * (acc[i][7] + bi) + r1.w;
    *reinterpret_cast<float4*>(&Ob[row]) = v0;
    *reinterpret_cast<float4*>(&Ob[row + 4]) = v1;
  }
}

// ---------------------------------------------------------------------------
// Flash attention on MFMA (bf16 in, fp32 accum).
// 256 threads = 4 waves: wave = (rhalf = w&1)*32 query rows x (h = w>>1)*64 keys.
// KB=128 keys/tile; K,V staged via global_load_lds with (row&7) chunk-XOR
// swizzle (pre-swizzled global source, linear LDS dest). P: D-layout -> LDS
// bf16 (swizzled, wave-private) -> A-frags. Team merge (h=0 vs h=1) at end.
// LDS 80KB -> 2 blocks/CU.
// ---------------------------------------------------------------------------
__global__ __launch_bounds__(256, 2) void flash_attn_mfma(
    const unsigned short* __restrict__ Qt,
    const unsigned short* __restrict__ Kt,
    const unsigned short* __restrict__ Vn,
    float* __restrict__ Og)
{
  __shared__ __align__(16) unsigned char smem[81920];
  unsigned short* Ks = (unsigned short*)smem;            // [128 key][128 c] bf16, swizzled
  unsigned short* Vs = (unsigned short*)(smem + 32768);  // [128 c][128 key] bf16, swizzled
  unsigned short* Ps = (unsigned short*)(smem + 65536);  // [4 wave][32 row][64 key] bf16

  const int flat = blockIdx.y * 64 + blockIdx.x;
  const int swz = (flat & 7) * 32 + (flat >> 3);   // XCD-aware, bijective (256%8==0)
  const int b = swz >> 6;
  const int n0 = (swz & 63) * 64;

  const int tid = threadIdx.x;
  const int w = tid >> 6;
  const int lane = tid & 63;
  const int l15 = lane & 15;
  const int g = lane >> 4;
  const int rhalf = w & 1;   // query-row half
  const int h = w >> 1;      // key-half team

  const unsigned short* Qb = Qt + (size_t)b * NN * CH;
  const unsigned short* Kb = Kt + (size_t)b * NN * CH;
  const unsigned short* Vb = Vn + (size_t)b * CH * NN;

  // Q fragments in registers: A[m=row][k=c], lane row = l15, k = g*8+i
  s8b qf[2][4];
#pragma unroll
  for (int m = 0; m < 2; ++m)
#pragma unroll
    for (int kk = 0; kk < 4; ++kk) {
      int row = n0 + rhalf * 32 + m * 16 + l15;
      int c = kk * 32 + g * 8;
      qf[m][kk] = *reinterpret_cast<const s8b*>(Qb + (size_t)row * CH + c);
    }

  f32x4 facc[2][8];
#pragma unroll
  for (int m = 0; m < 2; ++m)
#pragma unroll
    for (int cst = 0; cst < 8; ++cst)
#pragma unroll
      for (int r = 0; r < 4; ++r) facc[m][cst][r] = 0.f;
  float m_run[2][4], l_run[2][4];
#pragma unroll
  for (int m = 0; m < 2; ++m)
#pragma unroll
    for (int r = 0; r < 4; ++r) { m_run[m][r] = -1e30f; l_run[m][r] = 0.f; }

  for (int kt = 0; kt < 32; ++kt) {
    const int m0 = kt * 128;
    __syncthreads();  // previous tile's LDS reads complete
    // stage K tile [128 key][128 c] and V tile [128 c][128 key], 16B/lane,
    // swizzle applied on the GLOBAL source (chunk ^= row&7), LDS linear.
#pragma unroll
    for (int i = 0; i < 8; ++i) {
      const int loff = w * 8192 + i * 1024 + lane * 16;
      const int row = loff >> 8;            // key (Ks) / channel (Vs)
      const int chunk = (loff >> 4) & 15;
      const int sk = chunk ^ (row & 7);
      GLOAD16(Kb + (size_t)(m0 + row) * CH + sk * 8, smem + (w * 8192 + i * 1024));
      GLOAD16(Vb + (size_t)row * NN + m0 + sk * 8,
              smem + 32768 + w * 8192 + i * 1024);
    }
    __syncthreads();  // drains vmcnt: tiles ready

    // ---- stage 1: S[row][key] = Q . K^T (per wave: 32 rows x 64 keys) ----
    f32x4 sacc[2][4];
#pragma unroll
    for (int m = 0; m < 2; ++m)
#pragma unroll
      for (int st = 0; st < 4; ++st)
#pragma unroll
        for (int r = 0; r < 4; ++r) sacc[m][st][r] = 0.f;
#pragma unroll
    for (int kk = 0; kk < 4; ++kk)
#pragma unroll
      for (int st = 0; st < 4; ++st) {
        int key = h * 64 + st * 16 + l15;
        int ck = (kk * 4 + g) ^ (key & 7);
        s8b bf = *reinterpret_cast<const s8b*>(Ks + key * 128 + ck * 8);
        sacc[0][st] = MFMA16(qf[0][kk], bf, sacc[0][st]);
        sacc[1][st] = MFMA16(qf[1][kk], bf, sacc[1][st]);
      }

    // ---- online softmax (rows live in 16-lane groups; reduce over l15) ----
#pragma unroll
    for (int m = 0; m < 2; ++m)
#pragma unroll
      for (int r = 0; r < 4; ++r) {
        float s0 = sacc[m][0][r], s1 = sacc[m][1][r];
        float s2 = sacc[m][2][r], s3 = sacc[m][3][r];
        float t = fmaxf(fmaxf(s0, s1), fmaxf(s2, s3));
        t = fmaxf(t, __shfl_xor(t, 1));
        t = fmaxf(t, __shfl_xor(t, 2));
        t = fmaxf(t, __shfl_xor(t, 4));
        t = fmaxf(t, __shfl_xor(t, 8));
        float mn = fmaxf(m_run[m][r], t);
        float f = __expf(m_run[m][r] - mn);
        float p0 = __expf(s0 - mn), p1 = __expf(s1 - mn);
        float p2 = __expf(s2 - mn), p3 = __expf(s3 - mn);
        float rs = (p0 + p1) + (p2 + p3);
        rs += __shfl_xor(rs, 1);
        rs += __shfl_xor(rs, 2);
        rs += __shfl_xor(rs, 4);
        rs += __shfl_xor(rs, 8);
        l_run[m][r] = l_run[m][r] * f + rs;
        m_run[m][r] = mn;
#pragma unroll
        for (int cst = 0; cst < 8; ++cst) facc[m][cst][r] *= f;
        // write P (bf16) into wave-private LDS, row-XOR swizzled
        const int rw = m * 16 + g * 4 + r;
        unsigned short* pw = Ps + w * 2048 + rw * 64;
        float pv[4] = {p0, p1, p2, p3};
#pragma unroll
        for (int st = 0; st < 4; ++st) {
          int kc = st * 16 + l15;
          int ck = ((kc >> 3) ^ rw) & 7;
          pw[ck * 8 + (kc & 7)] = f2bf(pv[st]);
        }
      }

    // ---- stage 2: O += P . V  (A = P from own LDS, B = V shared) ----
    s8b pa[2][2];
#pragma unroll
    for (int m = 0; m < 2; ++m)
#pragma unroll
      for (int kk = 0; kk < 2; ++kk) {
        int rw = m * 16 + l15;
        int ck = ((kk * 4 + g) ^ rw) & 7;
        pa[m][kk] = *reinterpret_cast<const s8b*>(Ps + w * 2048 + rw * 64 + ck * 8);
      }
#pragma unroll
    for (int kk = 0; kk < 2; ++kk)
#pragma unroll
      for (int cst = 0; cst < 8; ++cst) {
        int c = cst * 16 + l15;
        int ck = (h * 8 + kk * 4 + g) ^ (c & 7);
        s8b vf = *reinterpret_cast<const s8b*>(Vs + c * 128 + ck * 8);
        facc[0][cst] = MFMA16(pa[0][kk], vf, facc[0][cst]);
        facc[1][cst] = MFMA16(pa[1][kk], vf, facc[1][cst]);
      }
  }

  // ---- epilogue: merge key-half teams, transpose, store [C][N] fp32 ----
  __syncthreads();
  float* Mb = (float*)(smem + 80896);  // [2][64]
  float* Lb = (float*)(smem + 81408);  // [2][64]
  if (l15 == 0) {
#pragma unroll
    for (int m = 0; m < 2; ++m)
#pragma unroll
      for (int r = 0; r < 4; ++r) {
        int ra = rhalf * 32 + m * 16 + g * 4 + r;
        Mb[h * 64 + ra] = m_run[m][r];
        Lb[h * 64 + ra] = l_run[m][r];
      }
  }
  __syncthreads();
  float* Obuf = (float*)smem;  // [64 row][128 c]
  if (h == 1) {
#pragma unroll
    for (int m = 0; m < 2; ++m)
#pragma unroll
      for (int r = 0; r < 4; ++r) {
        int ra = rhalf * 32 + m * 16 + g * 4 + r;
        float mt = fmaxf(Mb[ra], m_run[m][r]);
        float e1 = __expf(m_run[m][r] - mt);
#pragma unroll
        for (int cst = 0; cst < 8; ++cst)
          Obuf[ra * 128 + cst * 16 + l15] = facc[m][cst][r] * e1;
      }
  }
  __syncthreads();
  float* Obuf2 = (float*)(smem + 32768);  // [128 c][68]
  if (h == 0) {
#pragma unroll
    for (int m = 0; m < 2; ++m)
#pragma unroll
      for (int r = 0; r < 4; ++r) {
        int ra = rhalf * 32 + m * 16 + g * 4 + r;
        float m1 = Mb[64 + ra], l1 = Lb[64 + ra];
        float mt = fmaxf(m_run[m][r], m1);
        float e0 = __expf(m_run[m][r] - mt);
        float e1 = __expf(m1 - mt);
        float linv = 1.f / (l_run[m][r] * e0 + l1 * e1);
#pragma unroll
        for (int cst = 0; cst < 8; ++cst) {
          float v = (facc[m][cst][r] * e0 + Obuf[ra * 128 + cst * 16 + l15]) * linv;
          Obuf2[(cst * 16 + l15) * 68 + ra] = v;
        }
      }
  }
  __syncthreads();
  float* Ob = Og + (size_t)b * CH * NN;
#pragma unroll
  for (int i = 0; i < 32; ++i) {
    int idx = i * 256 + tid;
    int c = idx >> 6;
    int n = idx & 63;
    Ob[(size_t)c * NN + n0 + n] = Obuf2[c * 68 + n];
  }
}

// ---------------------------------------------------------------------------
extern "C" void kernel_launch(void* const* d_in, const int* in_sizes, int n_in,
                              void* d_out, int out_size, void* d_ws, size_t ws_size,
                              hipStream_t stream) {
  const float* x     = (const float*)d_in[0];
  const float* wq    = (const float*)d_in[1];
  const float* bq    = (const float*)d_in[2];
  const float* wk    = (const float*)d_in[3];
  const float* bk    = (const float*)d_in[4];
  const float* wv    = (const float*)d_in[5];
  const float* bv    = (const float*)d_in[6];
  const float* wo    = (const float*)d_in[7];
  const float* bo    = (const float*)d_in[8];
  const float* gamma = (const float*)d_in[9];
  float* y = (float*)d_out;

  const size_t per_bf = (size_t)BN * NN * CH;  // 2M elems
  unsigned short* Qt = (unsigned short*)d_ws;            // [B][N][C] bf16, 4MB
  unsigned short* Kt = Qt + per_bf;                      // [B][N][C] bf16, 4MB
  unsigned short* Vn = Kt + per_bf;                      // [B][C][N] bf16, 4MB
  float* O = (float*)(Vn + per_bf);                      // [B][C][N] fp32, 8MB

  qkv_proj<<<dim3(NN / 128, BN, 3), 256, 0, stream>>>(x, wq, bq, wk, bk, wv, bv,
                                                      Qt, Kt, Vn);
  flash_attn_mfma<<<dim3(64, BN), 256, 0, stream>>>(Qt, Kt, Vn, O);
  out_proj<<<dim3(NN / 128, BN), 256, 0, stream>>>(O, wo, bo, x, gamma, y);
}

// Round 4
// 202.016 us; speedup vs baseline: 3.5747x; 1.2749x over previous
//
#include <hip/hip_runtime.h>

#define BN 4
#define CH 128
#define NN 4096
#define SCALE_Q 0.088388347648318447f  // 1/sqrt(128)

typedef __attribute__((ext_vector_type(8))) short s8b;    // 8 x bf16 (4 VGPR)
typedef __attribute__((ext_vector_type(4))) float f32x4;  // MFMA C/D
typedef __attribute__((ext_vector_type(8))) unsigned short us8;
typedef __attribute__((ext_vector_type(4))) unsigned short us4;

#define MFMA16(a, b, c) __builtin_amdgcn_mfma_f32_16x16x32_bf16((a), (b), (c), 0, 0, 0)

#define GLOAD16(gsrc, ldst) __builtin_amdgcn_global_load_lds( \
    (const __attribute__((address_space(1))) unsigned int*)(gsrc), \
    (__attribute__((address_space(3))) unsigned int*)(ldst), 16, 0, 0)

__device__ __forceinline__ unsigned short f2bf(float f) {
  union { float f; unsigned int u; } v; v.f = f;
  unsigned int r = v.u + 0x7fffu + ((v.u >> 16) & 1u);  // RNE
  return (unsigned short)(r >> 16);
}
__device__ __forceinline__ float bf2f(unsigned short h) {
  union { unsigned int u; float f; } v; v.u = (unsigned int)h << 16;
  return v.f;
}

// ---------------------------------------------------------------------------
// transpose_x: x [B][C][N] fp32 -> Xth/Xtl [B][N][C] bf16 (hi/lo split).
// grid (N/64, B), 256 threads. LDS transpose with (n&7)<<3 chunk-XOR swizzle.
// ---------------------------------------------------------------------------
__global__ __launch_bounds__(256) void transpose_x(
    const float* __restrict__ x, unsigned short* __restrict__ Xth,
    unsigned short* __restrict__ Xtl)
{
  __shared__ unsigned short Lh[64 * 128];
  __shared__ unsigned short Ll[64 * 128];
  const int b = blockIdx.y;
  const int n0 = blockIdx.x * 64;
  const float* Xb = x + (size_t)b * CH * NN;
  const int tid = threadIdx.x;

#pragma unroll
  for (int it = 0; it < 8; ++it) {
    int idx = it * 256 + tid;          // 2048 float4 units
    int c = idx >> 4;
    int n4 = (idx & 15) * 4;
    float4 v = *reinterpret_cast<const float4*>(&Xb[(size_t)c * NN + n0 + n4]);
    float vv[4] = {v.x, v.y, v.z, v.w};
#pragma unroll
    for (int k = 0; k < 4; ++k) {
      int n = n4 + k;
      unsigned short hh = f2bf(vv[k]);
      unsigned short ll = f2bf(vv[k] - bf2f(hh));
      int ad = n * 128 + (c ^ ((n & 7) << 3));
      Lh[ad] = hh;
      Ll[ad] = ll;
    }
  }
  __syncthreads();
#pragma unroll
  for (int it = 0; it < 4; ++it) {
    int idx = it * 256 + tid;          // 1024 chunks of 8
    int n = idx >> 4;
    int j = idx & 15;
    int ad = n * 128 + ((j * 8) ^ ((n & 7) << 3));
    us8 h8 = *reinterpret_cast<const us8*>(&Lh[ad]);
    us8 l8 = *reinterpret_cast<const us8*>(&Ll[ad]);
    size_t go = ((size_t)b * NN + n0 + n) * CH + j * 8;
    *reinterpret_cast<us8*>(&Xth[go]) = h8;
    *reinterpret_cast<us8*>(&Xtl[go]) = l8;
  }
}

// ---------------------------------------------------------------------------
// qkv_mfma: split-bf16 MFMA projection. grid (N/64, B, 3), 256 thr (4 waves).
// Wave w owns o in [w*32, w*32+32). W fragments (hi/lo) live in registers.
// X tile (hi/lo) staged via global_load_lds, (row&7) chunk-XOR swizzle.
// Outputs: z=0 Qt[n][c] bf16*SCALE_Q, z=1 Kt[n][c], z=2 Vn[c][n].
// ---------------------------------------------------------------------------
__global__ __launch_bounds__(256, 3) void qkv_mfma(
    const unsigned short* __restrict__ Xth, const unsigned short* __restrict__ Xtl,
    const float* __restrict__ wq, const float* __restrict__ bq,
    const float* __restrict__ wk, const float* __restrict__ bk,
    const float* __restrict__ wv, const float* __restrict__ bv,
    unsigned short* __restrict__ Qt, unsigned short* __restrict__ Kt,
    unsigned short* __restrict__ Vn)
{
  __shared__ __align__(16) unsigned short Xh[64 * 128];  // 16KB
  __shared__ __align__(16) unsigned short Xl[64 * 128];  // 16KB

  const int b = blockIdx.y;
  const int n0 = blockIdx.x * 64;
  const int z = blockIdx.z;
  const float* W; const float* bias;
  if (z == 0)      { W = wq; bias = bq; }
  else if (z == 1) { W = wk; bias = bk; }
  else             { W = wv; bias = bv; }

  const int tid = threadIdx.x;
  const int w = tid >> 6, lane = tid & 63, l15 = lane & 15, g = lane >> 4;
  const int ob = w * 32;

  // stage X hi/lo (swizzled source, linear LDS dest)
  const unsigned short* XhB = Xth + ((size_t)b * NN + n0) * CH;
  const unsigned short* XlB = Xtl + ((size_t)b * NN + n0) * CH;
#pragma unroll
  for (int i = 0; i < 4; ++i) {
    int base = i * 4096 + w * 1024;
    int loff = base + lane * 16;
    int row = loff >> 8;
    int chunk = (loff >> 4) & 15;
    int sk = chunk ^ (row & 7);
    GLOAD16(XhB + (size_t)row * CH + sk * 8, ((unsigned char*)Xh) + base);
    GLOAD16(XlB + (size_t)row * CH + sk * 8, ((unsigned char*)Xl) + base);
  }

  // W fragments (hi/lo) straight from global into registers
  s8b ah[2][4], al[2][4];
#pragma unroll
  for (int m = 0; m < 2; ++m)
#pragma unroll
    for (int kk = 0; kk < 4; ++kk) {
      int o = ob + m * 16 + l15;
      int c = (kk * 4 + g) * 8;
      float4 w0 = *reinterpret_cast<const float4*>(&W[o * CH + c]);
      float4 w1 = *reinterpret_cast<const float4*>(&W[o * CH + c + 4]);
      float wv8[8] = {w0.x, w0.y, w0.z, w0.w, w1.x, w1.y, w1.z, w1.w};
      s8b hh, ll;
#pragma unroll
      for (int t = 0; t < 8; ++t) {
        unsigned short hv = f2bf(wv8[t]);
        hh[t] = (short)hv;
        ll[t] = (short)f2bf(wv8[t] - bf2f(hv));
      }
      ah[m][kk] = hh;
      al[m][kk] = ll;
    }
  __syncthreads();

  f32x4 acc[2][4];
#pragma unroll
  for (int m = 0; m < 2; ++m)
#pragma unroll
    for (int nst = 0; nst < 4; ++nst)
#pragma unroll
      for (int r = 0; r < 4; ++r) acc[m][nst][r] = 0.f;

#pragma unroll
  for (int kk = 0; kk < 4; ++kk)
#pragma unroll
    for (int nst = 0; nst < 4; ++nst) {
      int n = nst * 16 + l15;
      int ck = (kk * 4 + g) ^ (n & 7);
      s8b bh = *reinterpret_cast<const s8b*>(&Xh[n * 128 + ck * 8]);
      s8b bl = *reinterpret_cast<const s8b*>(&Xl[n * 128 + ck * 8]);
#pragma unroll
      for (int m = 0; m < 2; ++m) {
        acc[m][nst] = MFMA16(ah[m][kk], bh, acc[m][nst]);
        acc[m][nst] = MFMA16(ah[m][kk], bl, acc[m][nst]);
        acc[m][nst] = MFMA16(al[m][kk], bh, acc[m][nst]);
      }
    }
  __syncthreads();  // X LDS dead; reuse Xh as epilogue bounce

  if (z < 2) {
    // Out[n][c] = (acc + bias) * scale, bounce via Xh [64 n][128 c], slot4-XOR
    const float s = (z == 0) ? SCALE_Q : 1.f;
#pragma unroll
    for (int m = 0; m < 2; ++m) {
      float4 b4 = *reinterpret_cast<const float4*>(&bias[ob + m * 16 + g * 4]);
      float bb[4] = {b4.x, b4.y, b4.z, b4.w};
#pragma unroll
      for (int nst = 0; nst < 4; ++nst) {
        int n = nst * 16 + l15;
        int slot = w * 8 + m * 4 + g;
        int sl = slot ^ (n & 7);
        us4 pk;
#pragma unroll
        for (int r = 0; r < 4; ++r) pk[r] = f2bf((acc[m][nst][r] + bb[r]) * s);
        *reinterpret_cast<us4*>(&Xh[n * 128 + sl * 4]) = pk;
      }
    }
    __syncthreads();
    unsigned short* T = (z == 0 ? Qt : Kt) + ((size_t)b * NN + n0) * CH;
#pragma unroll
    for (int it = 0; it < 4; ++it) {
      int idx = it * 256 + tid;  // 1024 = 64n x 16 chunks
      int n = idx >> 4;
      int j = idx & 15;
      int s0 = (2 * j) ^ (n & 7);
      int s1 = (2 * j + 1) ^ (n & 7);
      us4 a4 = *reinterpret_cast<const us4*>(&Xh[n * 128 + s0 * 4]);
      us4 b4 = *reinterpret_cast<const us4*>(&Xh[n * 128 + s1 * 4]);
      us8 o8;
#pragma unroll
      for (int t = 0; t < 4; ++t) { o8[t] = a4[t]; o8[4 + t] = b4[t]; }
      *reinterpret_cast<us8*>(&T[n * CH + j * 8]) = o8;
    }
  } else {
    // V[c][n]: bounce via Xh [128 o][64 n], n-chunk XOR (o&7)
#pragma unroll
    for (int m = 0; m < 2; ++m) {
      float4 b4 = *reinterpret_cast<const float4*>(&bias[ob + m * 16 + g * 4]);
      float bb[4] = {b4.x, b4.y, b4.z, b4.w};
#pragma unroll
      for (int nst = 0; nst < 4; ++nst) {
        int n = nst * 16 + l15;
#pragma unroll
        for (int r = 0; r < 4; ++r) {
          int o = ob + m * 16 + g * 4 + r;
          Xh[o * 64 + (n ^ ((o & 7) << 3))] = f2bf(acc[m][nst][r] + bb[r]);
        }
      }
    }
    __syncthreads();
    unsigned short* V = Vn + (size_t)b * CH * NN;
#pragma unroll
    for (int it = 0; it < 4; ++it) {
      int idx = it * 256 + tid;  // 1024 = 128 o x 8 chunks
      int o = idx >> 3;
      int j8 = idx & 7;
      us8 v8 = *reinterpret_cast<const us8*>(&Xh[o * 64 + ((j8 ^ (o & 7)) << 3)]);
      *reinterpret_cast<us8*>(&V[(size_t)o * NN + n0 + j8 * 8]) = v8;
    }
  }
}

// ---------------------------------------------------------------------------
// Flash attention v2: 512 thr = 8 waves = 2 row-halves x 4 key-quarters.
// QB=64 rows/block, KB=128 keys/tile, K/V double-buffered (T3 prefetch).
// LDS: Ks[2]32KB + Vs[2]32KB + P 16KB = 144KB -> 1 block/CU, 2 waves/SIMD.
// Output: Oth/Otl [B][N][C] bf16 hi/lo (feeds out_mfma directly).
// ---------------------------------------------------------------------------
#define FLASH_STAGE(BI, KT) do {                                            \
    int m0_ = (KT) * 128;                                                   \
    _Pragma("unroll")                                                       \
    for (int i_ = 0; i_ < 4; ++i_) {                                        \
      int base_ = i_ * 8192 + w * 1024;                                     \
      int loff_ = base_ + lane * 16;                                        \
      int row_ = loff_ >> 8;                                                \
      int chunk_ = (loff_ >> 4) & 15;                                       \
      int sk_ = chunk_ ^ (row_ & 7);                                        \
      GLOAD16(Kb + (size_t)(m0_ + row_) * CH + sk_ * 8,                     \
              smem + (BI) * 32768 + base_);                                 \
      GLOAD16(Vb + (size_t)row_ * NN + m0_ + sk_ * 8,                       \
              smem + 65536 + (BI) * 32768 + base_);                         \
    }                                                                       \
  } while (0)

__global__ __launch_bounds__(512, 2) void flash_attn_mfma(
    const unsigned short* __restrict__ Qt,
    const unsigned short* __restrict__ Kt,
    const unsigned short* __restrict__ Vn,
    unsigned short* __restrict__ Oth, unsigned short* __restrict__ Otl)
{
  __shared__ __align__(16) unsigned char smem[147456];

  const int flat = blockIdx.y * 64 + blockIdx.x;
  const int swz = (flat & 7) * 32 + (flat >> 3);  // XCD-aware, bijective
  const int b = swz >> 6;
  const int n0 = (swz & 63) * 64;

  const int tid = threadIdx.x;
  const int w = tid >> 6, lane = tid & 63, l15 = lane & 15, g = lane >> 4;
  const int rhalf = w & 1;  // query-row half (32 rows)
  const int h = w >> 1;     // key quarter (32 keys of the 128-tile)

  const unsigned short* Qb = Qt + (size_t)b * NN * CH;
  const unsigned short* Kb = Kt + (size_t)b * NN * CH;
  const unsigned short* Vb = Vn + (size_t)b * CH * NN;

  // Q fragments
  s8b qf[2][4];
#pragma unroll
  for (int m = 0; m < 2; ++m)
#pragma unroll
    for (int kk = 0; kk < 4; ++kk) {
      int row = n0 + rhalf * 32 + m * 16 + l15;
      int c = (kk * 4 + g) * 8;
      qf[m][kk] = *reinterpret_cast<const s8b*>(&Qb[(size_t)row * CH + c]);
    }

  f32x4 facc[2][8];
#pragma unroll
  for (int m = 0; m < 2; ++m)
#pragma unroll
    for (int cst = 0; cst < 8; ++cst)
#pragma unroll
      for (int r = 0; r < 4; ++r) facc[m][cst][r] = 0.f;
  float m_run[2][4], l_run[2][4];
#pragma unroll
  for (int m = 0; m < 2; ++m)
#pragma unroll
    for (int r = 0; r < 4; ++r) { m_run[m][r] = -1e30f; l_run[m][r] = 0.f; }

  FLASH_STAGE(0, 0);
  __syncthreads();

  int cur = 0;
  for (int kt = 0; kt < 32; ++kt) {
    if (kt + 1 < 32) FLASH_STAGE(cur ^ 1, kt + 1);
    const unsigned short* Ks = (const unsigned short*)(smem + cur * 32768);
    const unsigned short* Vs = (const unsigned short*)(smem + 65536 + cur * 32768);
    unsigned short* Pw = (unsigned short*)(smem + 131072 + w * 2048);  // [32][32]

    // ---- QK^T: 32 rows x 32 keys per wave ----
    f32x4 sacc[2][2];
#pragma unroll
    for (int m = 0; m < 2; ++m)
#pragma unroll
      for (int st = 0; st < 2; ++st)
#pragma unroll
        for (int r = 0; r < 4; ++r) sacc[m][st][r] = 0.f;
#pragma unroll
    for (int kk = 0; kk < 4; ++kk)
#pragma unroll
      for (int st = 0; st < 2; ++st) {
        int key = h * 32 + st * 16 + l15;
        int ck = (kk * 4 + g) ^ (key & 7);
        s8b bf = *reinterpret_cast<const s8b*>(&Ks[key * 128 + ck * 8]);
        sacc[0][st] = MFMA16(qf[0][kk], bf, sacc[0][st]);
        sacc[1][st] = MFMA16(qf[1][kk], bf, sacc[1][st]);
      }

    // ---- online softmax + P write (wave-private, chunk-XOR swizzled) ----
#pragma unroll
    for (int m = 0; m < 2; ++m)
#pragma unroll
      for (int r = 0; r < 4; ++r) {
        float s0 = sacc[m][0][r], s1 = sacc[m][1][r];
        float t = fmaxf(s0, s1);
        t = fmaxf(t, __shfl_xor(t, 1));
        t = fmaxf(t, __shfl_xor(t, 2));
        t = fmaxf(t, __shfl_xor(t, 4));
        t = fmaxf(t, __shfl_xor(t, 8));
        float mn = fmaxf(m_run[m][r], t);
        float f = __expf(m_run[m][r] - mn);
        float p0 = __expf(s0 - mn), p1 = __expf(s1 - mn);
        float rs = p0 + p1;
        rs += __shfl_xor(rs, 1);
        rs += __shfl_xor(rs, 2);
        rs += __shfl_xor(rs, 4);
        rs += __shfl_xor(rs, 8);
        l_run[m][r] = l_run[m][r] * f + rs;
        m_run[m][r] = mn;
#pragma unroll
        for (int cst = 0; cst < 8; ++cst) facc[m][cst][r] *= f;
        int rw = m * 16 + g * 4 + r;
        int k0 = l15, k1 = 16 + l15;
        Pw[rw * 32 + (((k0 >> 3) ^ (rw & 3)) << 3) + (k0 & 7)] = f2bf(p0);
        Pw[rw * 32 + (((k1 >> 3) ^ (rw & 3)) << 3) + (k1 & 7)] = f2bf(p1);
      }

    // ---- PV: O += P . V ----
    s8b pa[2];
#pragma unroll
    for (int m = 0; m < 2; ++m) {
      int rw = m * 16 + l15;
      int kc = g ^ (rw & 3);
      pa[m] = *reinterpret_cast<const s8b*>(&Pw[rw * 32 + (kc << 3)]);
    }
#pragma unroll
    for (int cst = 0; cst < 8; ++cst) {
      int c = cst * 16 + l15;
      int ck = (h * 4 + g) ^ (c & 7);
      s8b vf = *reinterpret_cast<const s8b*>(&Vs[c * 128 + ck * 8]);
      facc[0][cst] = MFMA16(pa[0], vf, facc[0][cst]);
      facc[1][cst] = MFMA16(pa[1], vf, facc[1][cst]);
    }
    __syncthreads();  // prefetch landed + all reads of cur done
    cur ^= 1;
  }

  // ---- epilogue: merge 4 key-teams, store Ot hi/lo [N][C] ----
  float* Mb = (float*)smem;            // [4][64]
  float* Lb = (float*)(smem + 1024);   // [4][64]
  float* Db = (float*)(smem + 2048);   // [64] inverse denominators
  float* Obuf = (float*)(smem + 4096); // [64][132] fp32

  if (l15 == 0) {
#pragma unroll
    for (int m = 0; m < 2; ++m)
#pragma unroll
      for (int r = 0; r < 4; ++r) {
        int ra = rhalf * 32 + m * 16 + g * 4 + r;
        Mb[h * 64 + ra] = m_run[m][r];
        Lb[h * 64 + ra] = l_run[m][r];
      }
  }
  __syncthreads();
  float fsc[2][4];
#pragma unroll
  for (int m = 0; m < 2; ++m)
#pragma unroll
    for (int r = 0; r < 4; ++r) {
      int ra = rhalf * 32 + m * 16 + g * 4 + r;
      float M = fmaxf(fmaxf(Mb[ra], Mb[64 + ra]), fmaxf(Mb[128 + ra], Mb[192 + ra]));
      fsc[m][r] = __expf(m_run[m][r] - M);
      if (h == 0 && l15 == 0) {
        float den = Lb[ra] * __expf(Mb[ra] - M) + Lb[64 + ra] * __expf(Mb[64 + ra] - M) +
                    Lb[128 + ra] * __expf(Mb[128 + ra] - M) +
                    Lb[192 + ra] * __expf(Mb[192 + ra] - M);
        Db[ra] = 1.f / den;
      }
    }
  __syncthreads();
#pragma unroll
  for (int t = 0; t < 4; ++t) {
    if (h == t) {
#pragma unroll
      for (int m = 0; m < 2; ++m)
#pragma unroll
        for (int cst = 0; cst < 8; ++cst)
#pragma unroll
          for (int r = 0; r < 4; ++r) {
            int ra = rhalf * 32 + m * 16 + g * 4 + r;
            int c = cst * 16 + l15;
            float v = facc[m][cst][r] * fsc[m][r];
            if (t == 0) Obuf[ra * 132 + c] = v;
            else        Obuf[ra * 132 + c] += v;
          }
    }
    __syncthreads();
  }
#pragma unroll
  for (int it = 0; it < 2; ++it) {
    int idx = it * 512 + tid;  // 1024 = 64 rows x 16 chunks
    int row = idx >> 4;
    int j = idx & 15;
    float inv = Db[row];
    us8 hh, ll;
#pragma unroll
    for (int t = 0; t < 8; ++t) {
      float v = Obuf[row * 132 + j * 8 + t] * inv;
      unsigned short hv = f2bf(v);
      hh[t] = hv;
      ll[t] = f2bf(v - bf2f(hv));
    }
    size_t go = ((size_t)b * NN + n0 + row) * CH + j * 8;
    *reinterpret_cast<us8*>(&Oth[go]) = hh;
    *reinterpret_cast<us8*>(&Otl[go]) = ll;
  }
}

// ---------------------------------------------------------------------------
// out_mfma: y = gamma*(wo@O + bo) + x, split-bf16 MFMA, O from Oth/Otl [N][C].
// grid (N/64, B), 256 thr. Epilogue bounces through fp32 LDS for f4 stores.
// ---------------------------------------------------------------------------
__global__ __launch_bounds__(256, 2) void out_mfma(
    const unsigned short* __restrict__ Oth, const unsigned short* __restrict__ Otl,
    const float* __restrict__ wo, const float* __restrict__ bo,
    const float* __restrict__ x, const float* __restrict__ gamma,
    float* __restrict__ y)
{
  __shared__ __align__(16) unsigned char smem[67584];  // Oh 16K | Ol 16K | Obuf [128][68] f32
  unsigned short* Oh = (unsigned short*)smem;
  unsigned short* Ol = (unsigned short*)(smem + 16384);
  float* Obuf = (float*)(smem + 32768);

  const int b = blockIdx.y;
  const int n0 = blockIdx.x * 64;
  const int tid = threadIdx.x;
  const int w = tid >> 6, lane = tid & 63, l15 = lane & 15, g = lane >> 4;
  const int ob = w * 32;

  const unsigned short* OhB = Oth + ((size_t)b * NN + n0) * CH;
  const unsigned short* OlB = Otl + ((size_t)b * NN + n0) * CH;
#pragma unroll
  for (int i = 0; i < 4; ++i) {
    int base = i * 4096 + w * 1024;
    int loff = base + lane * 16;
    int row = loff >> 8;
    int chunk = (loff >> 4) & 15;
    int sk = chunk ^ (row & 7);
    GLOAD16(OhB + (size_t)row * CH + sk * 8, smem + base);
    GLOAD16(OlB + (size_t)row * CH + sk * 8, smem + 16384 + base);
  }

  s8b ah[2][4], al[2][4];
#pragma unroll
  for (int m = 0; m < 2; ++m)
#pragma unroll
    for (int kk = 0; kk < 4; ++kk) {
      int o = ob + m * 16 + l15;
      int c = (kk * 4 + g) * 8;
      float4 w0 = *reinterpret_cast<const float4*>(&wo[o * CH + c]);
      float4 w1 = *reinterpret_cast<const float4*>(&wo[o * CH + c + 4]);
      float wv8[8] = {w0.x, w0.y, w0.z, w0.w, w1.x, w1.y, w1.z, w1.w};
      s8b hh, ll;
#pragma unroll
      for (int t = 0; t < 8; ++t) {
        unsigned short hv = f2bf(wv8[t]);
        hh[t] = (short)hv;
        ll[t] = (short)f2bf(wv8[t] - bf2f(hv));
      }
      ah[m][kk] = hh;
      al[m][kk] = ll;
    }
  const float gm = gamma[0];
  __syncthreads();

  f32x4 acc[2][4];
#pragma unroll
  for (int m = 0; m < 2; ++m)
#pragma unroll
    for (int nst = 0; nst < 4; ++nst)
#pragma unroll
      for (int r = 0; r < 4; ++r) acc[m][nst][r] = 0.f;

#pragma unroll
  for (int kk = 0; kk < 4; ++kk)
#pragma unroll
    for (int nst = 0; nst < 4; ++nst) {
      int n = nst * 16 + l15;
      int ck = (kk * 4 + g) ^ (n & 7);
      s8b bh = *reinterpret_cast<const s8b*>(&Oh[n * 128 + ck * 8]);
      s8b bl = *reinterpret_cast<const s8b*>(&Ol[n * 128 + ck * 8]);
#pragma unroll
      for (int m = 0; m < 2; ++m) {
        acc[m][nst] = MFMA16(ah[m][kk], bh, acc[m][nst]);
        acc[m][nst] = MFMA16(ah[m][kk], bl, acc[m][nst]);
        acc[m][nst] = MFMA16(al[m][kk], bh, acc[m][nst]);
      }
    }
  __syncthreads();

#pragma unroll
  for (int m = 0; m < 2; ++m) {
    float4 b4 = *reinterpret_cast<const float4*>(&bo[ob + m * 16 + g * 4]);
    float bb[4] = {b4.x, b4.y, b4.z, b4.w};
#pragma unroll
    for (int nst = 0; nst < 4; ++nst) {
      int n = nst * 16 + l15;
#pragma unroll
      for (int r = 0; r < 4; ++r) {
        int o = ob + m * 16 + g * 4 + r;
        Obuf[o * 68 + n] = gm * (acc[m][nst][r] + bb[r]);
      }
    }
  }
  __syncthreads();
  const float* Xb = x + (size_t)b * CH * NN;
  float* Yb = y + (size_t)b * CH * NN;
#pragma unroll
  for (int it = 0; it < 8; ++it) {
    int idx = it * 256 + tid;  // 2048 = 128 o x 16 f4-chunks
    int o = idx >> 4;
    int n4 = (idx & 15) * 4;
    float4 v = *reinterpret_cast<const float4*>(&Obuf[o * 68 + n4]);
    float4 rx = *reinterpret_cast<const float4*>(&Xb[(size_t)o * NN + n0 + n4]);
    v.x += rx.x; v.y += rx.y; v.z += rx.z; v.w += rx.w;
    *reinterpret_cast<float4*>(&Yb[(size_t)o * NN + n0 + n4]) = v;
  }
}

// ---------------------------------------------------------------------------
extern "C" void kernel_launch(void* const* d_in, const int* in_sizes, int n_in,
                              void* d_out, int out_size, void* d_ws, size_t ws_size,
                              hipStream_t stream) {
  const float* x     = (const float*)d_in[0];
  const float* wq    = (const float*)d_in[1];
  const float* bq    = (const float*)d_in[2];
  const float* wk    = (const float*)d_in[3];
  const float* bk    = (const float*)d_in[4];
  const float* wv    = (const float*)d_in[5];
  const float* bv    = (const float*)d_in[6];
  const float* wo    = (const float*)d_in[7];
  const float* bo    = (const float*)d_in[8];
  const float* gamma = (const float*)d_in[9];
  float* y = (float*)d_out;

  const size_t per = (size_t)BN * NN * CH;  // 2M bf16 elems = 4MB
  unsigned short* Xth = (unsigned short*)d_ws;  // [B][N][C] hi
  unsigned short* Xtl = Xth + per;              // [B][N][C] lo
  unsigned short* Qt  = Xtl + per;              // [B][N][C]
  unsigned short* Kt  = Qt + per;               // [B][N][C]
  unsigned short* Vn  = Kt + per;               // [B][C][N]
  unsigned short* Oth = Vn + per;               // [B][N][C] hi
  unsigned short* Otl = Oth + per;              // [B][N][C] lo

  transpose_x<<<dim3(NN / 64, BN), 256, 0, stream>>>(x, Xth, Xtl);
  qkv_mfma<<<dim3(NN / 64, BN, 3), 256, 0, stream>>>(Xth, Xtl, wq, bq, wk, bk,
                                                     wv, bv, Qt, Kt, Vn);
  flash_attn_mfma<<<dim3(64, BN), 512, 0, stream>>>(Qt, Kt, Vn, Oth, Otl);
  out_mfma<<<dim3(NN / 64, BN), 256, 0, stream>>>(Oth, Otl, wo, bo, x, gamma, y);
}